// Round 9
// baseline (442.247 us; speedup 1.0000x reference)
//
#include <hip/hip_runtime.h>
#include <stdint.h>

typedef float f32x4 __attribute__((ext_vector_type(4)));
typedef int   i32x8 __attribute__((ext_vector_type(8)));
typedef long  i64x2 __attribute__((ext_vector_type(2)));

#define FP8_MAX_V 448.0f

// Pack 4 floats -> 4 OCP e4m3fn bytes, RNE, after reference-matching clip.
__device__ __forceinline__ uint32_t pack4_fp8(float a, float b, float c, float d) {
    a = fminf(fmaxf(a, -FP8_MAX_V), FP8_MAX_V);
    b = fminf(fmaxf(b, -FP8_MAX_V), FP8_MAX_V);
    c = fminf(fmaxf(c, -FP8_MAX_V), FP8_MAX_V);
    d = fminf(fmaxf(d, -FP8_MAX_V), FP8_MAX_V);
    int v = 0;
    v = __builtin_amdgcn_cvt_pk_fp8_f32(a, b, v, false);  // bytes 0,1
    v = __builtin_amdgcn_cvt_pk_fp8_f32(c, d, v, true);   // bytes 2,3
    return (uint32_t)v;
}

__global__ void quant_fp8_kernel(const float* __restrict__ in,
                                 uint32_t* __restrict__ out,
                                 const float* __restrict__ scale_ptr,
                                 long long n4) {
    const float s = scale_ptr[0];
    long long i = (long long)blockIdx.x * blockDim.x + threadIdx.x;
    const long long stride = (long long)gridDim.x * blockDim.x;
    const float4* in4 = (const float4*)in;
    for (; i < n4; i += stride) {
        float4 v = in4[i];
        out[i] = pack4_fp8(v.x / s, v.y / s, v.z / s, v.w / s);
    }
}

// MX-scaled fp8 GEMM, B-DIRECT variant. For NT GEMM the 16x16x128 fragment
// (lane l: row l&15, bytes [lg*32,+32)) is a row-major global slice, so B
// fragments load straight from global (L2-resident panel) into registers —
// no LDS, no barrier involvement, halving the LDS pipe load that bound
// r4/r6/r8 at ~330 us. A keeps the verified LDS path (2-wave reuse):
// ring-2 x 32 KiB slots, distance-1 stage, ONE vmcnt(8) + ONE s_barrier
// per K-tile. B double-buffered in regs, prefetch distance 1 (compiler
// inserts the counted vmcnt for reg deps). BM=256, BN=128, BK=128 B,
// 4 waves (2M x 2N), wave tile 128x64, acc 8x4xf32x4 (-> AGPR per r6).
// LDS swizzle: 16B slot = chunk ^ (row&7) on global SOURCE + ds_read addr.
__global__ __launch_bounds__(256, 2) void gemm_mxfp8_kernel(
    const uint8_t* __restrict__ qA,   // [M][K] fp8
    const uint8_t* __restrict__ qB,   // [N][K] fp8
    const float* __restrict__ bias,   // [N]
    const float* __restrict__ s_in_p,
    const float* __restrict__ s_w_p,
    float* __restrict__ C,            // [M][N] fp32
    int M, int N, int K) {
    __shared__ uint8_t lds[2][32768]; // A ring-2: [256 rows][128 B]

    const int tid = threadIdx.x;
    const int w   = tid >> 6;   // wave 0..3
    const int l   = tid & 63;
    const int wr  = w >> 1;     // A rows [wr*128, +128)
    const int wc  = w & 1;      // B rows [wc*64, +64)
    const int lr  = l & 15;     // fragment row
    const int lg  = l >> 4;     // k-group: bytes [lg*32, +32)
    const int lsw = lr & 7;     // XOR swizzle key

    // XCD-bijective block swizzle: grid = 1792 = 8 * 224.
    const int cpx = (int)gridDim.x >> 3;
    const int swz = ((int)blockIdx.x & 7) * cpx + ((int)blockIdx.x >> 3);
    const int bm  = (swz & 15) << 8;   // M/256 = 16 tiles
    const int bn  = (swz >> 4) << 7;   // N/128 = 112 tiles

    const float outscale = s_in_p[0] * s_w_p[0];
    const int NT = K >> 7;             // 32 K-tiles of 128 B (even)

    // A ds_read: two b128 at slots (2lg)^lsw, (2lg+1)^lsw of the frag row.
    const int off0 = (((lg << 1) ^ lsw) << 4);
    const int off1 = off0 ^ 16;

    f32x4 acc[8][4];
#pragma unroll
    for (int mi = 0; mi < 8; ++mi)
#pragma unroll
        for (int ni = 0; ni < 4; ++ni)
            acc[mi][ni] = (f32x4){0.f, 0.f, 0.f, 0.f};

    // A staging: thread t covers row=t>>3 (32 rows/issue), chunk t&7 with
    // source pre-swizzle (row&7); 8 issues of 4 KiB per tile.
    const int srow = tid >> 3;
    const int sc   = (((tid & 7) ^ (srow & 7)) << 4);
    const uint8_t* sA = qA + (size_t)(bm + srow) * K + sc;
    const int dstw = w << 10;   // linear LDS dest: wave base + lane*16 (HW)

    // B fragment row pointers (per lane): row = bn + wc*64 + ni*16 + lr.
    const uint8_t* bR0 = qB + (size_t)(bn + wc * 64 +  0 + lr) * K + (lg << 5);
    const uint8_t* bR1 = qB + (size_t)(bn + wc * 64 + 16 + lr) * K + (lg << 5);
    const uint8_t* bR2 = qB + (size_t)(bn + wc * 64 + 32 + lr) * K + (lg << 5);
    const uint8_t* bR3 = qB + (size_t)(bn + wc * 64 + 48 + lr) * K + (lg << 5);

    union frag { i32x8 v; i64x2 h[2]; };
    frag pb0[4], pb1[4];

#define STAGE_A(SL, KB) do { \
    _Pragma("unroll") \
    for (int i = 0; i < 8; ++i) { \
        __builtin_amdgcn_global_load_lds( \
            (const __attribute__((address_space(1))) void*)(sA + (size_t)(i * 32) * K + (KB)), \
            (__attribute__((address_space(3))) void*)(&lds[SL][0] + i * 4096 + dstw), 16, 0, 0); \
    } } while (0)

#define LOAD_B(BUF, KB) do { \
    BUF[0].h[0] = *(const i64x2*)(bR0 + (KB));      BUF[0].h[1] = *(const i64x2*)(bR0 + (KB) + 16); \
    BUF[1].h[0] = *(const i64x2*)(bR1 + (KB));      BUF[1].h[1] = *(const i64x2*)(bR1 + (KB) + 16); \
    BUF[2].h[0] = *(const i64x2*)(bR2 + (KB));      BUF[2].h[1] = *(const i64x2*)(bR2 + (KB) + 16); \
    BUF[3].h[0] = *(const i64x2*)(bR3 + (KB));      BUF[3].h[1] = *(const i64x2*)(bR3 + (KB) + 16); \
} while (0)

// One K-tile: stage A(T+1), issue B(T+1) regs, MFMA(A(T) LDS, B(T) regs).
// vmcnt(8): the 8 A-stages (issued first) landed; 8 B loads stay in flight
// across the barrier — their reg use next tile gets a compiler-counted wait.
#define TILE_BODY(TT, SLOT, BCUR, BNXT) do { \
    const int tn = ((TT) + 1 < NT) ? (TT) + 1 : 0; \
    STAGE_A((SLOT) ^ 1, tn << 7); \
    __builtin_amdgcn_sched_barrier(0); \
    LOAD_B(BNXT, (size_t)tn << 7); \
    __builtin_amdgcn_sched_barrier(0); \
    const uint8_t* sbase = &lds[SLOT][0]; \
    _Pragma("unroll") \
    for (int mi = 0; mi < 8; ++mi) { \
        frag ua; \
        const uint8_t* p = sbase + ((wr * 128 + mi * 16 + lr) << 7); \
        ua.h[0] = *(const i64x2*)(p + off0); \
        ua.h[1] = *(const i64x2*)(p + off1); \
        _Pragma("unroll") \
        for (int ni = 0; ni < 4; ++ni) \
            acc[mi][ni] = __builtin_amdgcn_mfma_scale_f32_16x16x128_f8f6f4( \
                ua.v, BCUR[ni].v, acc[mi][ni], 0, 0, 0, 127, 0, 127); \
    } \
    asm volatile("s_waitcnt lgkmcnt(0)" ::: "memory"); \
    __builtin_amdgcn_sched_barrier(0); \
    asm volatile("s_waitcnt vmcnt(8)" ::: "memory"); \
    __builtin_amdgcn_s_barrier(); \
} while (0)

    // Prologue: A(0) -> slot 0, B(0) -> pb0; full drain once; barrier.
    STAGE_A(0, 0);
    LOAD_B(pb0, 0);
    asm volatile("s_waitcnt vmcnt(0)" ::: "memory");
    __builtin_amdgcn_s_barrier();

    for (int T = 0; T < NT; T += 2) {   // NT even; static buffer naming
        TILE_BODY(T,     0, pb0, pb1);
        TILE_BODY(T + 1, 1, pb1, pb0);
    }

    // Epilogue. 16x16 C/D layout: col = lane&15, row = (lane>>4)*4 + reg.
    const int crow0 = bm + wr * 128 + (lg << 2);
    const int ccol0 = bn + wc * 64 + lr;
#pragma unroll
    for (int ni = 0; ni < 4; ++ni) {
        const int col = ccol0 + ni * 16;
        const float bv = bias[col];
#pragma unroll
        for (int mi = 0; mi < 8; ++mi) {
            const int row = crow0 + mi * 16;
#pragma unroll
            for (int r = 0; r < 4; ++r)
                C[(size_t)(row + r) * N + col] = acc[mi][ni][r] * outscale + bv;
        }
    }
#undef STAGE_A
#undef LOAD_B
#undef TILE_BODY
}

extern "C" void kernel_launch(void* const* d_in, const int* in_sizes, int n_in,
                              void* d_out, int out_size, void* d_ws, size_t ws_size,
                              hipStream_t stream) {
    const float* x    = (const float*)d_in[0];
    const float* wt   = (const float*)d_in[1];
    const float* bias = (const float*)d_in[2];
    const float* s_in = (const float*)d_in[3];
    const float* s_w  = (const float*)d_in[4];
    float* out = (float*)d_out;

    const long long xe = in_sizes[0];            // M*K
    const long long we = in_sizes[1];            // N*K
    const int N = in_sizes[2];
    const int K = (int)(we / N);
    const int M = (int)(xe / K);

    uint8_t* qx = (uint8_t*)d_ws;                // M*K fp8
    uint8_t* qw = qx + xe;                       // N*K fp8

    quant_fp8_kernel<<<2048, 256, 0, stream>>>(x,  (uint32_t*)qx, s_in, xe >> 2);
    quant_fp8_kernel<<<2048, 256, 0, stream>>>(wt, (uint32_t*)qw, s_w,  we >> 2);

    dim3 grid((M / 256) * (N / 128));            // 16*112 = 1792 (8 | 1792)
    gemm_mxfp8_kernel<<<grid, 256, 0, stream>>>(qx, qw, bias, s_in, s_w, out,
                                                M, N, K);
}

// Round 10
// 441.867 us; speedup vs baseline: 1.0009x; 1.0009x over previous
//
#include <hip/hip_runtime.h>
#include <stdint.h>

typedef float f32x4 __attribute__((ext_vector_type(4)));
typedef int   i32x8 __attribute__((ext_vector_type(8)));
typedef long  i64x2 __attribute__((ext_vector_type(2)));

#define FP8_MAX_V 448.0f

// Pack 4 floats -> 4 OCP e4m3fn bytes, RNE, after reference-matching clip.
__device__ __forceinline__ uint32_t pack4_fp8(float a, float b, float c, float d) {
    a = fminf(fmaxf(a, -FP8_MAX_V), FP8_MAX_V);
    b = fminf(fmaxf(b, -FP8_MAX_V), FP8_MAX_V);
    c = fminf(fmaxf(c, -FP8_MAX_V), FP8_MAX_V);
    d = fminf(fmaxf(d, -FP8_MAX_V), FP8_MAX_V);
    int v = 0;
    v = __builtin_amdgcn_cvt_pk_fp8_f32(a, b, v, false);  // bytes 0,1
    v = __builtin_amdgcn_cvt_pk_fp8_f32(c, d, v, true);   // bytes 2,3
    return (uint32_t)v;
}

__global__ void quant_fp8_kernel(const float* __restrict__ in,
                                 uint32_t* __restrict__ out,
                                 const float* __restrict__ scale_ptr,
                                 long long n4) {
    const float s = scale_ptr[0];
    long long i = (long long)blockIdx.x * blockDim.x + threadIdx.x;
    const long long stride = (long long)gridDim.x * blockDim.x;
    const float4* in4 = (const float4*)in;
    for (; i < n4; i += stride) {
        float4 v = in4[i];
        out[i] = pack4_fp8(v.x / s, v.y / s, v.z / s, v.w / s);
    }
}

// MX-scaled fp8 GEMM, B-DIRECT variant. For NT GEMM the 16x16x128 fragment
// (lane l: row l&15, bytes [lg*32,+32)) is a row-major global slice, so B
// fragments load straight from global (L2-resident panel) into registers —
// no LDS, no barrier involvement, halving the LDS pipe load that bound
// r4/r6/r8 at ~330 us. A keeps the verified LDS path (2-wave reuse):
// ring-2 x 32 KiB slots, distance-1 stage, ONE vmcnt(8) + ONE s_barrier
// per K-tile. B double-buffered in regs, prefetch distance 1 (compiler
// inserts the counted vmcnt for reg deps). BM=256, BN=128, BK=128 B,
// 4 waves (2M x 2N), wave tile 128x64, acc 8x4xf32x4 (-> AGPR per r6).
// LDS swizzle: 16B slot = chunk ^ (row&7) on global SOURCE + ds_read addr.
__global__ __launch_bounds__(256, 2) void gemm_mxfp8_kernel(
    const uint8_t* __restrict__ qA,   // [M][K] fp8
    const uint8_t* __restrict__ qB,   // [N][K] fp8
    const float* __restrict__ bias,   // [N]
    const float* __restrict__ s_in_p,
    const float* __restrict__ s_w_p,
    float* __restrict__ C,            // [M][N] fp32
    int M, int N, int K) {
    __shared__ uint8_t lds[2][32768]; // A ring-2: [256 rows][128 B]

    const int tid = threadIdx.x;
    const int w   = tid >> 6;   // wave 0..3
    const int l   = tid & 63;
    const int wr  = w >> 1;     // A rows [wr*128, +128)
    const int wc  = w & 1;      // B rows [wc*64, +64)
    const int lr  = l & 15;     // fragment row
    const int lg  = l >> 4;     // k-group: bytes [lg*32, +32)
    const int lsw = lr & 7;     // XOR swizzle key

    // XCD-bijective block swizzle: grid = 1792 = 8 * 224.
    const int cpx = (int)gridDim.x >> 3;
    const int swz = ((int)blockIdx.x & 7) * cpx + ((int)blockIdx.x >> 3);
    const int bm  = (swz & 15) << 8;   // M/256 = 16 tiles
    const int bn  = (swz >> 4) << 7;   // N/128 = 112 tiles

    const float outscale = s_in_p[0] * s_w_p[0];
    const int NT = K >> 7;             // 32 K-tiles of 128 B (even)

    // A ds_read: two b128 at slots (2lg)^lsw, (2lg+1)^lsw of the frag row.
    const int off0 = (((lg << 1) ^ lsw) << 4);
    const int off1 = off0 ^ 16;

    f32x4 acc[8][4];
#pragma unroll
    for (int mi = 0; mi < 8; ++mi)
#pragma unroll
        for (int ni = 0; ni < 4; ++ni)
            acc[mi][ni] = (f32x4){0.f, 0.f, 0.f, 0.f};

    // A staging: thread t covers row=t>>3 (32 rows/issue), chunk t&7 with
    // source pre-swizzle (row&7); 8 issues of 4 KiB per tile.
    const int srow = tid >> 3;
    const int sc   = (((tid & 7) ^ (srow & 7)) << 4);
    const uint8_t* sA = qA + (size_t)(bm + srow) * K + sc;
    const int dstw = w << 10;   // linear LDS dest: wave base + lane*16 (HW)

    // B fragment row pointers (per lane): row = bn + wc*64 + ni*16 + lr.
    const uint8_t* bR0 = qB + (size_t)(bn + wc * 64 +  0 + lr) * K + (lg << 5);
    const uint8_t* bR1 = qB + (size_t)(bn + wc * 64 + 16 + lr) * K + (lg << 5);
    const uint8_t* bR2 = qB + (size_t)(bn + wc * 64 + 32 + lr) * K + (lg << 5);
    const uint8_t* bR3 = qB + (size_t)(bn + wc * 64 + 48 + lr) * K + (lg << 5);

    union frag { i32x8 v; i64x2 h[2]; };
    frag pb0[4], pb1[4];

#define STAGE_A(SL, KB) do { \
    _Pragma("unroll") \
    for (int i = 0; i < 8; ++i) { \
        __builtin_amdgcn_global_load_lds( \
            (const __attribute__((address_space(1))) void*)(sA + (size_t)(i * 32) * K + (KB)), \
            (__attribute__((address_space(3))) void*)(&lds[SL][0] + i * 4096 + dstw), 16, 0, 0); \
    } } while (0)

#define LOAD_B(BUF, KB) do { \
    BUF[0].h[0] = *(const i64x2*)(bR0 + (KB));      BUF[0].h[1] = *(const i64x2*)(bR0 + (KB) + 16); \
    BUF[1].h[0] = *(const i64x2*)(bR1 + (KB));      BUF[1].h[1] = *(const i64x2*)(bR1 + (KB) + 16); \
    BUF[2].h[0] = *(const i64x2*)(bR2 + (KB));      BUF[2].h[1] = *(const i64x2*)(bR2 + (KB) + 16); \
    BUF[3].h[0] = *(const i64x2*)(bR3 + (KB));      BUF[3].h[1] = *(const i64x2*)(bR3 + (KB) + 16); \
} while (0)

// One K-tile: stage A(T+1), issue B(T+1) regs, MFMA(A(T) LDS, B(T) regs).
// vmcnt(8): the 8 A-stages (issued first) landed; 8 B loads stay in flight
// across the barrier — their reg use next tile gets a compiler-counted wait.
#define TILE_BODY(TT, SLOT, BCUR, BNXT) do { \
    const int tn = ((TT) + 1 < NT) ? (TT) + 1 : 0; \
    STAGE_A((SLOT) ^ 1, tn << 7); \
    __builtin_amdgcn_sched_barrier(0); \
    LOAD_B(BNXT, (size_t)tn << 7); \
    __builtin_amdgcn_sched_barrier(0); \
    const uint8_t* sbase = &lds[SLOT][0]; \
    _Pragma("unroll") \
    for (int mi = 0; mi < 8; ++mi) { \
        frag ua; \
        const uint8_t* p = sbase + ((wr * 128 + mi * 16 + lr) << 7); \
        ua.h[0] = *(const i64x2*)(p + off0); \
        ua.h[1] = *(const i64x2*)(p + off1); \
        _Pragma("unroll") \
        for (int ni = 0; ni < 4; ++ni) \
            acc[mi][ni] = __builtin_amdgcn_mfma_scale_f32_16x16x128_f8f6f4( \
                ua.v, BCUR[ni].v, acc[mi][ni], 0, 0, 0, 127, 0, 127); \
    } \
    asm volatile("s_waitcnt lgkmcnt(0)" ::: "memory"); \
    __builtin_amdgcn_sched_barrier(0); \
    asm volatile("s_waitcnt vmcnt(8)" ::: "memory"); \
    __builtin_amdgcn_s_barrier(); \
} while (0)

    // Prologue: A(0) -> slot 0, B(0) -> pb0; full drain once; barrier.
    STAGE_A(0, 0);
    LOAD_B(pb0, 0);
    asm volatile("s_waitcnt vmcnt(0)" ::: "memory");
    __builtin_amdgcn_s_barrier();

    for (int T = 0; T < NT; T += 2) {   // NT even; static buffer naming
        TILE_BODY(T,     0, pb0, pb1);
        TILE_BODY(T + 1, 1, pb1, pb0);
    }

    // Epilogue. 16x16 C/D layout: col = lane&15, row = (lane>>4)*4 + reg.
    const int crow0 = bm + wr * 128 + (lg << 2);
    const int ccol0 = bn + wc * 64 + lr;
#pragma unroll
    for (int ni = 0; ni < 4; ++ni) {
        const int col = ccol0 + ni * 16;
        const float bv = bias[col];
#pragma unroll
        for (int mi = 0; mi < 8; ++mi) {
            const int row = crow0 + mi * 16;
#pragma unroll
            for (int r = 0; r < 4; ++r)
                C[(size_t)(row + r) * N + col] = acc[mi][ni][r] * outscale + bv;
        }
    }
#undef STAGE_A
#undef LOAD_B
#undef TILE_BODY
}

extern "C" void kernel_launch(void* const* d_in, const int* in_sizes, int n_in,
                              void* d_out, int out_size, void* d_ws, size_t ws_size,
                              hipStream_t stream) {
    const float* x    = (const float*)d_in[0];
    const float* wt   = (const float*)d_in[1];
    const float* bias = (const float*)d_in[2];
    const float* s_in = (const float*)d_in[3];
    const float* s_w  = (const float*)d_in[4];
    float* out = (float*)d_out;

    const long long xe = in_sizes[0];            // M*K
    const long long we = in_sizes[1];            // N*K
    const int N = in_sizes[2];
    const int K = (int)(we / N);
    const int M = (int)(xe / K);

    uint8_t* qx = (uint8_t*)d_ws;                // M*K fp8
    uint8_t* qw = qx + xe;                       // N*K fp8

    quant_fp8_kernel<<<2048, 256, 0, stream>>>(x,  (uint32_t*)qx, s_in, xe >> 2);
    quant_fp8_kernel<<<2048, 256, 0, stream>>>(wt, (uint32_t*)qw, s_w,  we >> 2);

    dim3 grid((M / 256) * (N / 128));            // 16*112 = 1792 (8 | 1792)
    gemm_mxfp8_kernel<<<grid, 256, 0, stream>>>(qx, qw, bias, s_in, s_w, out,
                                                M, N, K);
}